// Round 2
// baseline (2613.084 us; speedup 1.0000x reference)
//
#include <hip/hip_runtime.h>
#include <cstddef>
#include <cstdint>

#define NN 16384
#define DD 64
#define EE 1048576
#define KSPLIT 8
#define BM 128
#define BK 32
#define KRANGE (NN / KSPLIT)  // 2048

typedef __attribute__((ext_vector_type(4))) float f4;

// ---------------------------------------------------------------------------
// big_gemm: P[split] = A[rows, krange] @ B[krange, 0:64]
// BM=128 rows/block, 64 cols, BK=32, 128 threads (2 waves), 8x8 micro-tile.
// FUSE_COPY: stream the staged A slab to Aout (the output tuple's A slot),
// eliminating the separate 1 GiB hipMemcpyAsync read pass.
// ---------------------------------------------------------------------------
template <bool FUSE_COPY>
__global__ __launch_bounds__(128) void big_gemm(const float* __restrict__ A,
                                                const float* __restrict__ B,
                                                float* __restrict__ P,
                                                float* __restrict__ Aout) {
  __shared__ __align__(16) float At[BK][BM + 4];  // transposed A tile: At[k][row]
  __shared__ __align__(16) float Bs[BK][DD + 4];  // Bs[k][col]

  const int tid = threadIdx.x;
  const int tx = tid & 7;    // 0..7  (col groups)
  const int ty = tid >> 3;   // 0..15 (row groups)
  const int row0 = blockIdx.x * BM;
  const int kbase0 = blockIdx.y * KRANGE;

  float acc[8][8];
#pragma unroll
  for (int i = 0; i < 8; ++i)
#pragma unroll
    for (int j = 0; j < 8; ++j) acc[i][j] = 0.f;

  const int arow = tid >> 3;  // 0..15
  const int akq = tid & 7;    // 0..7 -> k quad
  const int brow = tid >> 4;  // 0..7
  const int bc4 = tid & 15;   // 0..15 -> col quad

  for (int kt = 0; kt < KRANGE; kt += BK) {
    const int kb = kbase0 + kt;
    // stage A tile (128 rows x 32 k), transposing into At[k][row]
#pragma unroll
    for (int ps = 0; ps < 8; ++ps) {
      const int r = arow + ps * 16;
      const size_t off = (size_t)(row0 + r) * NN + kb + akq * 4;
      const f4 v = *reinterpret_cast<const f4*>(A + off);
      if (FUSE_COPY) *reinterpret_cast<f4*>(Aout + off) = v;
      At[akq * 4 + 0][r] = v[0];
      At[akq * 4 + 1][r] = v[1];
      At[akq * 4 + 2][r] = v[2];
      At[akq * 4 + 3][r] = v[3];
    }
    // stage B tile (32 k x 64 cols)
#pragma unroll
    for (int ps = 0; ps < 4; ++ps) {
      const int kk = brow + ps * 8;
      const f4 v = *reinterpret_cast<const f4*>(B + (size_t)(kb + kk) * DD + bc4 * 4);
      *reinterpret_cast<f4*>(&Bs[kk][bc4 * 4]) = v;
    }
    __syncthreads();

#pragma unroll 8
    for (int k = 0; k < BK; ++k) {
      const f4 a0 = *reinterpret_cast<const f4*>(&At[k][ty * 4]);
      const f4 a1 = *reinterpret_cast<const f4*>(&At[k][64 + ty * 4]);
      const f4 b0 = *reinterpret_cast<const f4*>(&Bs[k][tx * 4]);
      const f4 b1 = *reinterpret_cast<const f4*>(&Bs[k][32 + tx * 4]);
#pragma unroll
      for (int q = 0; q < 4; ++q) {
#pragma unroll
        for (int p = 0; p < 4; ++p) {
          acc[q][p] += a0[q] * b0[p];
          acc[q][p + 4] += a0[q] * b1[p];
          acc[q + 4][p] += a1[q] * b0[p];
          acc[q + 4][p + 4] += a1[q] * b1[p];
        }
      }
    }
    __syncthreads();
  }

  float* Pb = P + (size_t)blockIdx.y * NN * DD;
#pragma unroll
  for (int rg = 0; rg < 2; ++rg) {
#pragma unroll
    for (int q = 0; q < 4; ++q) {
      const int row = row0 + rg * 64 + ty * 4 + q;
      float* pr = Pb + (size_t)row * DD;
      f4 v0, v1;
#pragma unroll
      for (int p = 0; p < 4; ++p) {
        v0[p] = acc[rg * 4 + q][p];
        v1[p] = acc[rg * 4 + q][p + 4];
      }
      *reinterpret_cast<f4*>(pr + tx * 4) = v0;
      *reinterpret_cast<f4*>(pr + 32 + tx * 4) = v1;
    }
  }
}

// ---------------------------------------------------------------------------
// reduce_relu: H = relu(sum over KSPLIT partials)
// ---------------------------------------------------------------------------
__global__ void reduce_relu(const float* __restrict__ P, float* __restrict__ H) {
  const int idx = blockIdx.x * blockDim.x + threadIdx.x;  // float4 index, exact grid
  const f4* P4 = reinterpret_cast<const f4*>(P);
  f4 s = P4[idx];
#pragma unroll
  for (int sp = 1; sp < KSPLIT; ++sp) s += P4[(size_t)sp * NN * (DD / 4) + idx];
#pragma unroll
  for (int j = 0; j < 4; ++j) s[j] = s[j] > 0.f ? s[j] : 0.f;
  reinterpret_cast<f4*>(H)[idx] = s;
}

// ---------------------------------------------------------------------------
// row_gemm64: out[n][o] = sum_i in[n][i] * W[o][i]   (W is [64,64] row-major)
// ---------------------------------------------------------------------------
__global__ void row_gemm64(const float* __restrict__ in, const float* __restrict__ W,
                           float* __restrict__ out) {
  __shared__ __align__(16) float Xs[4][DD];
  const int tid = threadIdx.x;
  const int r = tid >> 6;
  const int o = tid & 63;
  const int row = blockIdx.x * 4 + r;
  Xs[r][o] = in[(size_t)row * DD + o];
  __syncthreads();
  const f4* wp = reinterpret_cast<const f4*>(W + (size_t)o * DD);
  const f4* xp = reinterpret_cast<const f4*>(&Xs[r][0]);
  float s = 0.f;
#pragma unroll
  for (int i = 0; i < 16; ++i) {
    const f4 w = wp[i];
    const f4 x = xp[i];
    s += w[0] * x[0] + w[1] * x[1] + w[2] * x[2] + w[3] * x[3];
  }
  out[(size_t)row * DD + o] = s;
}

// ---------------------------------------------------------------------------
// gab_kernel: Gab[n][0:64]  = H[n] @ W_l1[:, 0:64]^T + b   (G_a with bias folded)
//             Gab[n][64:128]= H[n] @ W_l1[:, 64:128]^T     (G_b)
// ---------------------------------------------------------------------------
__global__ void gab_kernel(const float* __restrict__ H, const float* __restrict__ Wl1,
                           const float* __restrict__ b, float* __restrict__ Gab) {
  __shared__ __align__(16) float Xs[2][DD];
  const int tid = threadIdx.x;
  const int r = tid >> 7;    // 0..1
  const int o = tid & 127;   // 0..127
  if (tid < 128) Xs[tid >> 6][tid & 63] = H[(size_t)(blockIdx.x * 2 + (tid >> 6)) * DD + (tid & 63)];
  __syncthreads();
  const int row = blockIdx.x * 2 + r;
  const float* wrow = Wl1 + (size_t)(o & 63) * 128 + (o >> 6) * 64;
  const f4* wp = reinterpret_cast<const f4*>(wrow);
  const f4* xp = reinterpret_cast<const f4*>(&Xs[r][0]);
  float s = (o < 64) ? b[o] : 0.f;
#pragma unroll
  for (int i = 0; i < 16; ++i) {
    const f4 w = wp[i];
    const f4 x = xp[i];
    s += w[0] * x[0] + w[1] * x[1] + w[2] * x[2] + w[3] * x[3];
  }
  Gab[(size_t)row * 128 + o] = s;
}

// ---------------------------------------------------------------------------
// edge_kernel: out[e] = sum_o W3[o] * sigmoid(Ga[src][o] + Gb[dst][o])
// 16 lanes per edge, float4 per lane, shfl_xor reduce within 16-lane group.
// ---------------------------------------------------------------------------
__global__ void edge_kernel(const float* __restrict__ Gab, const int* __restrict__ esrc,
                            const int* __restrict__ edst, const float* __restrict__ W3,
                            float* __restrict__ out, float* __restrict__ wn) {
  const int tid = threadIdx.x;
  const int sub = tid & 15;
  const int e = blockIdx.x * 16 + (tid >> 4);
  const int s = esrc[e];
  const int d = edst[e];
  const f4* gs = reinterpret_cast<const f4*>(Gab) + (size_t)s * 32;
  const f4* gd = reinterpret_cast<const f4*>(Gab) + (size_t)d * 32 + 16;
  const f4 ga = gs[sub];
  const f4 gb = gd[sub];
  const f4 w3 = reinterpret_cast<const f4*>(W3)[sub];
  float sum = 0.f;
#pragma unroll
  for (int j = 0; j < 4; ++j) {
    const float h = 1.0f / (1.0f + __expf(-(ga[j] + gb[j])));
    sum += w3[j] * h;
  }
  sum += __shfl_xor(sum, 1, 16);
  sum += __shfl_xor(sum, 2, 16);
  sum += __shfl_xor(sum, 4, 16);
  sum += __shfl_xor(sum, 8, 16);
  if (sub == 0) out[e] = sum;
  if (blockIdx.x == 0 && tid == 0) *wn = 0.f;
}

// ---------------------------------------------------------------------------
extern "C" void kernel_launch(void* const* d_in, const int* in_sizes, int n_in,
                              void* d_out, int out_size, void* d_ws, size_t ws_size,
                              hipStream_t stream) {
  const float* X = (const float*)d_in[0];
  const float* A = (const float*)d_in[1];
  const float* Wfc1 = (const float*)d_in[2];
  const float* Wfc3 = (const float*)d_in[3];
  const float* Wl1 = (const float*)d_in[4];
  const float* bl1 = (const float*)d_in[5];
  const float* Wl3 = (const float*)d_in[6];
  const int* esrc = (const int*)d_in[7];
  const int* edst = (const int*)d_in[8];
  float* out = (float*)d_out;

  // workspace layout (floats): P[8*N*64] | Bbuf[N*64] | H1[N*64] | H2[N*64] | Gab[N*128]
  float* Pbuf = (float*)d_ws;
  float* Bbuf = Pbuf + (size_t)KSPLIT * NN * DD;
  float* H1 = Bbuf + (size_t)NN * DD;
  float* H2 = H1 + (size_t)NN * DD;
  float* Gab = H2 + (size_t)NN * DD;

  // layer 1: H1 = relu(A @ (X @ Wfc1^T)); A pass-through fused into staging
  row_gemm64<<<NN / 4, 256, 0, stream>>>(X, Wfc1, Bbuf);
  big_gemm<true><<<dim3(NN / BM, KSPLIT), 128, 0, stream>>>(A, Bbuf, Pbuf, out + EE);
  reduce_relu<<<NN * (DD / 4) / 256, 256, 0, stream>>>(Pbuf, H1);

  // layer 2: H2 = relu(A @ (H1 @ Wfc3^T))
  row_gemm64<<<NN / 4, 256, 0, stream>>>(H1, Wfc3, Bbuf);
  big_gemm<false><<<dim3(NN / BM, KSPLIT), 128, 0, stream>>>(A, Bbuf, Pbuf, nullptr);
  reduce_relu<<<NN * (DD / 4) / 256, 256, 0, stream>>>(Pbuf, H2);

  // edge scorer tables + per-edge evaluation
  gab_kernel<<<NN / 2, 256, 0, stream>>>(H2, Wl1, bl1, Gab);
  edge_kernel<<<EE / 16, 256, 0, stream>>>(Gab, esrc, edst, Wl3, out,
                                           out + EE + (size_t)NN * NN);
}